// Round 16
// baseline (3997.393 us; speedup 1.0000x reference)
//
#include <hip/hip_runtime.h>
#include <hip/hip_bf16.h>

typedef long long i64;
typedef __attribute__((ext_vector_type(8))) short bf16x8;
typedef __attribute__((ext_vector_type(4))) float f32x4;

// ---- output element offsets (FLOAT32 elements — d_out is float*) ----
static constexpr i64 OUT_POLICY = 0;
static constexpr i64 OUT_VALUE  = 46336;
static constexpr i64 OUT_ZE0    = 46464;
static constexpr i64 OUT_ZE1    = 1525120;
static constexpr i64 OUT_ZE2    = 1590656;
static constexpr i64 OUT_ZQ0    = 1656192;
static constexpr i64 OUT_ZQ1    = 3134848;
static constexpr i64 OUT_ZQ2    = 3200384;
static constexpr i64 OUT_K0     = 3265920;
static constexpr i64 OUT_K1     = 3312128;
static constexpr i64 OUT_K2     = 3313152;
static constexpr i64 OUT_ZQL0   = 3314176;
static constexpr i64 OUT_ZQL1   = 4792832;
static constexpr i64 OUT_ZQL2   = 4858368;
static constexpr i64 OUT_EM0    = 4923904;
static constexpr i64 OUT_EM1    = 6402560;
static constexpr i64 OUT_EM2    = 6468096;
static constexpr i64 OUT_TOTAL  = 6533632;

__device__ __forceinline__ short bf16_hi(float v, float* back)
{
    unsigned b = __float_as_uint(v);
    unsigned hb = (b + 0x8000u) & 0xFFFF0000u;
    *back = __uint_as_float(hb);
    return (short)(hb >> 16);
}
__device__ __forceinline__ short bf16_of(float v)
{
    return (short)((__float_as_uint(v) + 0x8000u) >> 16);
}

// =============== weight transpose (f32 path) ===============
__global__ void wtr_k(const float* __restrict__ w, float* __restrict__ wt,
                      int COUT, int CIN)
{
    int total = COUT * CIN * 9;
    for (int idx = blockIdx.x * blockDim.x + threadIdx.x; idx < total;
         idx += gridDim.x * blockDim.x) {
        int co = idx / (CIN * 9);
        int r  = idx - co * CIN * 9;
        int ci = r / 9;
        int tap = r - ci * 9;
        wt[((i64)tap * CIN + ci) * COUT + co] = w[idx];
    }
}

// =============== MFMA weight prep: swizzled bf16 hi/lo tiles ===============
__global__ void wtr4_k(const float* __restrict__ w, short* __restrict__ wt4,
                       int CIN, int COUT)
{
    int NC = CIN / 32;
    int total = NC * 9 * 2 * 8192;
    for (int idx = blockIdx.x * blockDim.x + threadIdx.x; idx < total;
         idx += gridDim.x * blockDim.x) {
        int tile = idx >> 13;
        int pos  = idx & 8191;
        int row   = pos >> 6;
        int sslot = (pos >> 3) & 7;
        int r     = pos & 7;
        int slot  = sslot ^ (row & 7);
        int k2    = slot * 8 + r;
        int ct = tile & 1;
        int s  = tile >> 1;
        int c  = s / 9, t = s - c * 9;
        int co = ct * 128 + row;
        int ci = c * 32 + (k2 & 31);
        short outv = 0;
        if (co < COUT) {
            float v = w[((i64)co * CIN + ci) * 9 + t];
            float hf;
            short hs = bf16_hi(v, &hf);
            outv = (k2 < 32) ? hs : bf16_of(v - hf);
        }
        wt4[idx] = outv;
    }
}

// =============== MFMA conv 3x3: implicit GEMM, 4-term bf16 split ===============
// r13 base + (1) A-fragment register prefetch (ping/pong afA/afB, static idx)
// + (2) XCD-bijective block swizzle (m204) on the col-tile index.
// Same MFMA order/operands as round 13 -> bitwise-identical numerics.
template<int CIN>
__global__ __launch_bounds__(256)
void convmfma_k(const float* __restrict__ X, const short* __restrict__ WT4,
                float* __restrict__ Y, int coutT)
{
    constexpr int NC = CIN / 32;
    constexpr int NS = NC * 9;          // 72 (even)
    __shared__ short Bt[2][8192];
    const int tid  = threadIdx.x;
    const int lane = tid & 63;
    const int w    = tid >> 6;
    const int wco  = (w & 1) * 64;
    const int wsp  = (w >> 1) * 64;

    // XCD-bijective swizzle of the col-tile index (nwg=361, 361%8=1)
    const int q8 = (int)gridDim.x >> 3;
    const int r8 = (int)gridDim.x & 7;
    const int xcd = (int)blockIdx.x & 7;
    const int boff = (int)blockIdx.x >> 3;
    const int bcol = (xcd < r8) ? (xcd * (q8 + 1) + boff)
                                : (r8 * (q8 + 1) + (xcd - r8) * q8 + boff);
    const int col0 = bcol * 128;
    const int ct   = blockIdx.y;
    const int co0  = ct * 128;

    const int spS = tid & 127;
    const int cig = tid >> 7;
    const int colS = col0 + spS;
    const int nS = colS / 361;
    const int sS = colS - nS * 361;
    const int yS = sS / 19, xS = sS - yS * 19;
    const float* Xb = X + (i64)nS * CIN * 361 + sS;

    float xv[16];

#define B_LOAD(S)                                                               \
    {                                                                           \
        const int c_ = (S) / 9, t_ = (S) - c_ * 9;                              \
        const int ky_ = t_ / 3, kx_ = t_ - ky_ * 3;                             \
        const bool v_ = (yS + ky_ >= 1) & (yS + ky_ <= 19) &                    \
                        (xS + kx_ >= 1) & (xS + kx_ <= 19);                     \
        const float* xp_ = Xb + (i64)(c_ * 32 + cig * 16) * 361                 \
                              + (ky_ - 1) * 19 + (kx_ - 1);                     \
        _Pragma("unroll")                                                       \
        for (int j = 0; j < 16; j++) xv[j] = v_ ? xp_[(i64)j * 361] : 0.f;      \
    }

#define B_WRITE(BUF)                                                            \
    {                                                                           \
        bf16x8 h0, h1, l0, l1;                                                  \
        _Pragma("unroll")                                                       \
        for (int j = 0; j < 8; j++) {                                           \
            float hf;                                                           \
            short hs = bf16_hi(xv[j], &hf);                                     \
            h0[j] = hs; l0[j] = bf16_of(xv[j] - hf);                            \
        }                                                                       \
        _Pragma("unroll")                                                       \
        for (int j = 0; j < 8; j++) {                                           \
            float hf;                                                           \
            short hs = bf16_hi(xv[8 + j], &hf);                                 \
            h1[j] = hs; l1[j] = bf16_of(xv[8 + j] - hf);                        \
        }                                                                       \
        short* bp = &Bt[BUF][spS << 6];                                         \
        const int sw = spS & 7;                                                 \
        *(bf16x8*)(bp + (((cig * 2 + 0) ^ sw) << 3)) = h0;                      \
        *(bf16x8*)(bp + (((cig * 2 + 1) ^ sw) << 3)) = h1;                      \
        *(bf16x8*)(bp + (((4 + cig * 2 + 0) ^ sw) << 3)) = l0;                  \
        *(bf16x8*)(bp + (((4 + cig * 2 + 1) ^ sw) << 3)) = l1;                  \
    }

#define A_PREF(AFR, S)                                                          \
    {                                                                           \
        const short* tb_ = WT4 + ((i64)((S) * 2 + ct) << 13);                   \
        _Pragma("unroll")                                                       \
        for (int ha = 0; ha < 2; ha++)                                          \
            _Pragma("unroll")                                                   \
            for (int fa = 0; fa < 4; fa++) {                                    \
                int row = wco + fa * 16 + (lane & 15);                          \
                int slot = ha * 4 + (lane >> 4);                                \
                AFR[ha][fa] = *(const bf16x8*)(tb_ + (row << 6) + (((slot ^ (row & 7))) << 3)); \
            }                                                                   \
    }

#define COMPUTE(CUR, AFR)                                                       \
    {                                                                           \
        bf16x8 bfr[2][4];                                                       \
        _Pragma("unroll")                                                       \
        for (int hb = 0; hb < 2; hb++)                                          \
            _Pragma("unroll")                                                   \
            for (int fb = 0; fb < 4; fb++) {                                    \
                int row = wsp + fb * 16 + (lane & 15);                          \
                int slot = hb * 4 + (lane >> 4);                                \
                bfr[hb][fb] = *(const bf16x8*)&Bt[CUR][(row << 6) + (((slot ^ (row & 7))) << 3)]; \
            }                                                                   \
        _Pragma("unroll")                                                       \
        for (int ha = 0; ha < 2; ha++)                                          \
            _Pragma("unroll")                                                   \
            for (int fa = 0; fa < 4; fa++) {                                    \
                bf16x8 af = AFR[ha][fa];                                        \
                _Pragma("unroll")                                               \
                for (int hb = 0; hb < 2; hb++)                                  \
                    _Pragma("unroll")                                           \
                    for (int fb = 0; fb < 4; fb++)                              \
                        acc[fa][fb] = __builtin_amdgcn_mfma_f32_16x16x32_bf16(  \
                            af, bfr[hb][fb], acc[fa][fb], 0, 0, 0);             \
            }                                                                   \
    }

    f32x4 acc[4][4];
#pragma unroll
    for (int i = 0; i < 4; i++)
#pragma unroll
        for (int j = 0; j < 4; j++) acc[i][j] = (f32x4){0.f, 0.f, 0.f, 0.f};

    bf16x8 afA[2][4], afB[2][4];

    // prologue: step 0 staged into buf0; A(0) prefetched
    B_LOAD(0)
    B_WRITE(0)
    A_PREF(afA, 0)

    for (int s = 0; s < NS; s += 2) {
        __syncthreads();                       // buf0 ready
        B_LOAD(s + 1)                          // globals for s+1 in flight
        A_PREF(afB, s + 1)                     // A frags for s+1 in flight
        COMPUTE(0, afA)                        // step s (buf0, A preloaded)
        B_WRITE(1)                             // stage s+1 into buf1
        __syncthreads();                       // buf1 ready
        if (s + 2 < NS) {
            B_LOAD(s + 2)
            A_PREF(afA, s + 2)
        }
        COMPUTE(1, afB)                        // step s+1 (buf1)
        if (s + 2 < NS) B_WRITE(0)             // stage s+2 into buf0
    }
#undef B_LOAD
#undef B_WRITE
#undef A_PREF
#undef COMPUTE

#pragma unroll
    for (int fb = 0; fb < 4; fb++) {
        int col = col0 + wsp + fb * 16 + (lane & 15);
        int nT = col / 361, sT = col - nT * 361;
        float* yp = Y + ((i64)nT * coutT + co0 + wco) * 361 + sT;
#pragma unroll
        for (int fa = 0; fa < 4; fa++)
#pragma unroll
            for (int r = 0; r < 4; r++) {
                int m = fa * 16 + (lane >> 4) * 4 + r;
                if (co0 + wco + m < coutT) yp[(i64)m * 361] = acc[fa][fb][r];
            }
    }
}

// =============== f32 conv (CIN=18 first conv + fallback) ===============
template<int CIN>
__global__ __launch_bounds__(256)
void convgemm_k(const float* __restrict__ X, const float* __restrict__ wt,
                float* __restrict__ Y, int wtW, int coW0, int coutT)
{
    constexpr int NCB = (CIN + 15) / 16;
    constexpr int NS  = 9 * NCB;
    __shared__ float Ws[2][16][128];
    __shared__ float Bs[2][16][128];
    const int tid  = threadIdx.x;
    const int col0 = blockIdx.x * 128;
    const int co0  = blockIdx.y * 128;
    const int tn = tid & 15;
    const int tm = (tid >> 4) & 15;
    const int kkS  = tid >> 5;
    const int cS0  = (tid & 31) * 4;

    int y_[4], x_[4];
    const float* Xb[4];
#pragma unroll
    for (int j = 0; j < 4; j++) {
        int colj = col0 + cS0 + j;
        int nj = colj / 361;
        int sj = colj - nj * 361;
        y_[j] = sj / 19;
        x_[j] = sj - y_[j] * 19;
        Xb[j] = X + ((i64)nj * CIN) * 361 + sj;
    }

    float4 wA, wB, bA, bB;

#define STAGE(S)                                                               \
    {                                                                          \
        const int tap_ = (S) / NCB, cb_ = ((S) % NCB) * 16;                    \
        const int ky_ = tap_ / 3, kx_ = tap_ - ky_ * 3;                        \
        const int doff_ = (ky_ - 1) * 19 + (kx_ - 1);                          \
        const int ci0_ = cb_ + kkS, ci1_ = ci0_ + 8;                           \
        const float* wr_ = wt + ((i64)(tap_ * CIN) + ci0_) * wtW               \
                              + coW0 + co0 + cS0;                              \
        const bool wok_ = (coW0 + co0 + cS0) < wtW;                            \
        wA = (wok_ && ci0_ < CIN) ? *(const float4*)wr_                        \
                                  : float4{0.f, 0.f, 0.f, 0.f};                \
        wB = (wok_ && ci1_ < CIN) ? *(const float4*)(wr_ + (i64)8 * wtW)       \
                                  : float4{0.f, 0.f, 0.f, 0.f};                \
        bool v0_ = (y_[0]+ky_>=1)&(y_[0]+ky_<=19)&(x_[0]+kx_>=1)&(x_[0]+kx_<=19); \
        bool v1_ = (y_[1]+ky_>=1)&(y_[1]+ky_<=19)&(x_[1]+kx_>=1)&(x_[1]+kx_<=19); \
        bool v2_ = (y_[2]+ky_>=1)&(y_[2]+ky_<=19)&(x_[2]+kx_>=1)&(x_[2]+kx_<=19); \
        bool v3_ = (y_[3]+ky_>=1)&(y_[3]+ky_<=19)&(x_[3]+kx_>=1)&(x_[3]+kx_<=19); \
        bA.x = (v0_ && ci0_ < CIN) ? Xb[0][(i64)ci0_ * 361 + doff_] : 0.f;     \
        bA.y = (v1_ && ci0_ < CIN) ? Xb[1][(i64)ci0_ * 361 + doff_] : 0.f;     \
        bA.z = (v2_ && ci0_ < CIN) ? Xb[2][(i64)ci0_ * 361 + doff_] : 0.f;     \
        bA.w = (v3_ && ci0_ < CIN) ? Xb[3][(i64)ci0_ * 361 + doff_] : 0.f;     \
        bB.x = (v0_ && ci1_ < CIN) ? Xb[0][(i64)ci1_ * 361 + doff_] : 0.f;     \
        bB.y = (v1_ && ci1_ < CIN) ? Xb[1][(i64)ci1_ * 361 + doff_] : 0.f;     \
        bB.z = (v2_ && ci1_ < CIN) ? Xb[2][(i64)ci1_ * 361 + doff_] : 0.f;     \
        bB.w = (v3_ && ci1_ < CIN) ? Xb[3][(i64)ci1_ * 361 + doff_] : 0.f;     \
    }

#define WRITE(BUF)                                                             \
    {                                                                          \
        *(float4*)&Ws[BUF][kkS    ][cS0] = wA;                                 \
        *(float4*)&Ws[BUF][kkS + 8][cS0] = wB;                                 \
        *(float4*)&Bs[BUF][kkS    ][cS0] = bA;                                 \
        *(float4*)&Bs[BUF][kkS + 8][cS0] = bB;                                 \
    }

    float acc[8][8];
#pragma unroll
    for (int i = 0; i < 8; i++)
#pragma unroll
        for (int j = 0; j < 8; j++) acc[i][j] = 0.f;

    STAGE(0)
    WRITE(0)
    int cur = 0;
    for (int s = 0; s < NS; s++) {
        __syncthreads();
        if (s + 1 < NS) STAGE(s + 1)
#pragma unroll
        for (int kk = 0; kk < 16; kk++) {
            const float4 w0 = *(const float4*)&Ws[cur][kk][tm * 4];
            const float4 w1 = *(const float4*)&Ws[cur][kk][tm * 4 + 64];
            const float4 b0 = *(const float4*)&Bs[cur][kk][tn * 4];
            const float4 b1 = *(const float4*)&Bs[cur][kk][tn * 4 + 64];
            float wv[8] = {w0.x, w0.y, w0.z, w0.w, w1.x, w1.y, w1.z, w1.w};
            float bv[8] = {b0.x, b0.y, b0.z, b0.w, b1.x, b1.y, b1.z, b1.w};
#pragma unroll
            for (int wi = 0; wi < 8; wi++)
#pragma unroll
                for (int bj = 0; bj < 8; bj++)
                    acc[wi][bj] = fmaf(wv[wi], bv[bj], acc[wi][bj]);
        }
        if (s + 1 < NS) WRITE(cur ^ 1)
        cur ^= 1;
    }
#undef STAGE
#undef WRITE

#pragma unroll
    for (int bj = 0; bj < 8; bj++) {
        int lc = (bj < 4) ? (tn * 4 + bj) : (64 + tn * 4 + bj - 4);
        int colT = col0 + lc;
        int nT = colT / 361;
        int sT = colT - nT * 361;
        float* yp = Y + ((i64)nT * coutT + co0) * 361 + sT;
#pragma unroll
        for (int wi = 0; wi < 8; wi++) {
            int co = (wi < 4) ? (tm * 4 + wi) : (64 + tm * 4 + wi - 4);
            if (co0 + co < coutT) yp[(i64)co * 361] = acc[wi][bj];
        }
    }
}

// =============== BN batch-stats -> scale/shift ===============
__global__ __launch_bounds__(256)
void bnstats_k(const float* __restrict__ x, const float* __restrict__ g,
               const float* __restrict__ b, float* __restrict__ scale,
               float* __restrict__ shift, int C)
{
    const int c = blockIdx.x;
    float s = 0.f, s2 = 0.f;
    for (int n = 0; n < 128; n++) {
        const float* p = x + ((i64)n * C + c) * 361;
        for (int i = threadIdx.x; i < 361; i += 256) {
            float v = p[i]; s += v; s2 += v * v;
        }
    }
    __shared__ float rs[4], rq[4];
    for (int o = 32; o > 0; o >>= 1) { s += __shfl_down(s, o); s2 += __shfl_down(s2, o); }
    int lane = threadIdx.x & 63, wid = threadIdx.x >> 6;
    if (lane == 0) { rs[wid] = s; rq[wid] = s2; }
    __syncthreads();
    if (threadIdx.x == 0) {
        float S = rs[0] + rs[1] + rs[2] + rs[3];
        float Q = rq[0] + rq[1] + rq[2] + rq[3];
        const float inv = 1.f / 46208.f;
        float m  = S * inv;
        float var = Q * inv - m * m;
        float sc = g[c] * rsqrtf(var + 1e-5f);
        scale[c] = sc;
        shift[c] = b[c] - m * sc;
    }
}

// =============== BN apply (vectorized) ===============
__global__ void bn_relu4_k(float4* __restrict__ x, const float* __restrict__ scale,
                           const float* __restrict__ shift, int C, int total4)
{
    for (int i = blockIdx.x * blockDim.x + threadIdx.x; i < total4; i += gridDim.x * blockDim.x) {
        float4 v = x[i];
        int e = i * 4;
        int c0 = (e / 361) % C, c1 = ((e + 1) / 361) % C;
        int c2 = ((e + 2) / 361) % C, c3 = ((e + 3) / 361) % C;
        v.x = fmaf(v.x, scale[c0], shift[c0]); v.x = v.x > 0.f ? v.x : 0.f;
        v.y = fmaf(v.y, scale[c1], shift[c1]); v.y = v.y > 0.f ? v.y : 0.f;
        v.z = fmaf(v.z, scale[c2], shift[c2]); v.z = v.z > 0.f ? v.z : 0.f;
        v.w = fmaf(v.w, scale[c3], shift[c3]); v.w = v.w > 0.f ? v.w : 0.f;
        x[i] = v;
    }
}

__global__ void bn_add_relu4_k(float4* __restrict__ xa, const float4* __restrict__ xc,
                               const float* __restrict__ scale, const float* __restrict__ shift,
                               int C, int total4)
{
    for (int i = blockIdx.x * blockDim.x + threadIdx.x; i < total4; i += gridDim.x * blockDim.x) {
        float4 a = xa[i], c = xc[i];
        int e = i * 4;
        int c0 = (e / 361) % C, c1 = ((e + 1) / 361) % C;
        int c2 = ((e + 2) / 361) % C, c3 = ((e + 3) / 361) % C;
        a.x += fmaf(c.x, scale[c0], shift[c0]); a.x = a.x > 0.f ? a.x : 0.f;
        a.y += fmaf(c.y, scale[c1], shift[c1]); a.y = a.y > 0.f ? a.y : 0.f;
        a.z += fmaf(c.z, scale[c2], shift[c2]); a.z = a.z > 0.f ? a.z : 0.f;
        a.w += fmaf(c.w, scale[c3], shift[c3]); a.w = a.w > 0.f ? a.w : 0.f;
        xa[i] = a;
    }
}

__global__ void bn_tanh_ws_k(const float* __restrict__ x, const float* __restrict__ scale,
                             const float* __restrict__ shift, float* __restrict__ zf, int total)
{
    for (int i = blockIdx.x * blockDim.x + threadIdx.x; i < total; i += gridDim.x * blockDim.x) {
        int c = (i / 361) & 31;
        zf[i] = tanhf(fmaf(x[i], scale[c], shift[c]));
    }
}

// =============== codebook prep ===============
__global__ void prep_k(const float* __restrict__ E0, const float* __restrict__ E1,
                       const float* __restrict__ E2,
                       float* __restrict__ ee0, float* __restrict__ ee1, float* __restrict__ ee2,
                       float* __restrict__ cm0, float* __restrict__ cm1, float* __restrict__ cm2)
{
    int t = threadIdx.x;
    if (blockIdx.x == 0) {
        float s = 0.f; const float* e = E0 + (i64)t * 32;
        for (int d = 0; d < 32; d++) s += e[d] * e[d];
        ee0[t] = s;
    } else if (blockIdx.x == 1) {
        float s = 0.f; const float* e = E1 + (i64)t * 64;
        for (int d = 0; d < 64; d++) s += e[d] * e[d];
        ee1[t] = s;
    } else if (blockIdx.x == 2) {
        float s = 0.f; const float* e = E2 + (i64)t * 64;
        for (int d = 0; d < 64; d++) s += e[d] * e[d];
        ee2[t] = s;
    } else {
        if (t < 32) {
            float s = 0.f; for (int k = 0; k < 512; k++) s += E0[k * 32 + t];
            cm0[t] = s * (1.f / 512.f);
        } else if (t >= 64 && t < 128) {
            int d = t - 64; float s = 0.f; for (int k = 0; k < 512; k++) s += E1[k * 64 + d];
            cm1[d] = s * (1.f / 512.f);
        } else if (t >= 128 && t < 192) {
            int d = t - 128; float s = 0.f; for (int k = 0; k < 512; k++) s += E2[k * 64 + d];
            cm2[d] = s * (1.f / 512.f);
        }
    }
}

// =============== VQ kernels ===============
__global__ __launch_bounds__(256)
void vq0_k(const float* __restrict__ z, const float* __restrict__ E,
           const float* __restrict__ ee, float* __restrict__ zqf, int* __restrict__ ki)
{
    __shared__ float Es[256 * 32];
    int row = blockIdx.x * 256 + threadIdx.x;
    const bool live = row < 46208;
    const float* zp = z + (i64)(live ? row : 0) * 32;
    float zv[32]; float zz = 0.f;
#pragma unroll
    for (int d = 0; d < 32; d++) { float v = zp[d]; zv[d] = v; zz += v * v; }
    float best = 3.4e38f; int bk = 0;
    for (int h = 0; h < 2; h++) {
        __syncthreads();
        for (int i = threadIdx.x; i < 256 * 32; i += 256) Es[i] = E[h * 8192 + i];
        __syncthreads();
        for (int k = 0; k < 256; k++) {
            const float* e = Es + k * 32;
            float dot = 0.f;
#pragma unroll
            for (int d = 0; d < 32; d++) dot = fmaf(zv[d], e[d], dot);
            float dist = (zz + ee[h * 256 + k]) - 2.f * dot;
            if (dist < best) { best = dist; bk = h * 256 + k; }
        }
    }
    if (live) {
        ki[row] = bk;
        const float* eb = E + (i64)bk * 32;
#pragma unroll
        for (int d = 0; d < 32; d++) zqf[(i64)row * 32 + d] = eb[d];
    }
}

__global__ __launch_bounds__(256)
void vq64_k(const float* __restrict__ z, const float* __restrict__ E,
            const float* __restrict__ ee, float* __restrict__ zqf, int* __restrict__ ki)
{
    __shared__ float Es[128 * 64];
    int row = blockIdx.x * 256 + threadIdx.x;
    const float* zp = z + (i64)row * 64;
    float zv[64]; float zz = 0.f;
#pragma unroll
    for (int d = 0; d < 64; d++) { float v = zp[d]; zv[d] = v; zz += v * v; }
    float best = 3.4e38f; int bk = 0;
    for (int h = 0; h < 4; h++) {
        __syncthreads();
        for (int i = threadIdx.x; i < 128 * 64; i += 256) Es[i] = E[(i64)h * 8192 + i];
        __syncthreads();
        for (int k = 0; k < 128; k++) {
            const float* e = Es + k * 64;
            float dot = 0.f;
#pragma unroll
            for (int d = 0; d < 64; d++) dot = fmaf(zv[d], e[d], dot);
            float dist = (zz + ee[h * 128 + k]) - 2.f * dot;
            if (dist < best) { best = dist; bk = h * 128 + k; }
        }
    }
    ki[row] = bk;
    const float* eb = E + (i64)bk * 64;
#pragma unroll
    for (int d = 0; d < 64; d++) zqf[(i64)row * 64 + d] = eb[d];
}

// =============== split-K GEMM ===============
__global__ __launch_bounds__(256)
void gemm_part_k(const float* __restrict__ A, const float* __restrict__ W,
                 float* __restrict__ part, int K, int N, int kchunk)
{
    __shared__ float As[128][17];
    __shared__ float Ws[16][64];
    const int n0 = blockIdx.x * 64;
    const int ks = blockIdx.y;
    const int kb0  = ks * kchunk;
    const int kend = min(K, kb0 + kchunk);
    const int tid = threadIdx.x;
    const int tn = tid & 15, tm = tid >> 4;
    float acc[8][4];
#pragma unroll
    for (int i = 0; i < 8; i++)
#pragma unroll
        for (int j = 0; j < 4; j++) acc[i][j] = 0.f;

    for (int kb = kb0; kb < kend; kb += 16) {
        __syncthreads();
        for (int i = tid; i < 2048; i += 256) {
            int m = i >> 4, kk = i & 15;
            int k = kb + kk;
            As[m][kk] = (k < kend) ? A[(i64)m * K + k] : 0.f;
        }
        for (int i = tid; i < 1024; i += 256) {
            int kk = i >> 6, nl = i & 63;
            int k = kb + kk, n = n0 + nl;
            Ws[kk][nl] = (k < kend && n < N) ? W[(i64)k * N + n] : 0.f;
        }
        __syncthreads();
#pragma unroll
        for (int kk = 0; kk < 16; kk++) {
            float av[8], wv[4];
#pragma unroll
            for (int i = 0; i < 8; i++) av[i] = As[tm * 8 + i][kk];
#pragma unroll
            for (int j = 0; j < 4; j++) wv[j] = Ws[kk][tn * 4 + j];
#pragma unroll
            for (int i = 0; i < 8; i++)
#pragma unroll
                for (int j = 0; j < 4; j++) acc[i][j] = fmaf(av[i], wv[j], acc[i][j]);
        }
    }
#pragma unroll
    for (int i = 0; i < 8; i++) {
        int m = tm * 8 + i;
#pragma unroll
        for (int j = 0; j < 4; j++) {
            int n = n0 + tn * 4 + j;
            if (n < N) part[((i64)ks * 128 + m) * N + n] = acc[i][j];
        }
    }
}

__global__ void combine_k(const float* __restrict__ part, const float* __restrict__ bias,
                          float* __restrict__ of, int MN, int N, int ksplit, int act)
{
    for (int i = blockIdx.x * blockDim.x + threadIdx.x; i < MN; i += gridDim.x * blockDim.x) {
        float s = 0.f;
        for (int t = 0; t < ksplit; t++) s += part[(i64)t * MN + i];
        s += bias[i % N];
        if (act == 1) s = s > 0.f ? s : 0.f;
        else if (act == 2) s = tanhf(s);
        of[i] = s;
    }
}

__global__ void blend_k(const float* __restrict__ q, const float* __restrict__ d,
                        const float* __restrict__ hu, int col, float* __restrict__ o,
                        int per_b, int total)
{
    for (int i = blockIdx.x * blockDim.x + threadIdx.x; i < total; i += gridDim.x * blockDim.x) {
        float u = hu[(i / per_b) * 2 + col];
        o[i] = u * q[i] + (1.f - u) * d[i];
    }
}

__global__ __launch_bounds__(256)
void value_k(const float* __restrict__ x, const float* __restrict__ w,
             const float* __restrict__ b, float* __restrict__ valf)
{
    int m = blockIdx.x;
    float s = 0.f;
    const float* xp = x + (i64)m * 11552;
    for (int k = threadIdx.x; k < 11552; k += 256) s = fmaf(xp[k], w[k], s);
    for (int o = 32; o > 0; o >>= 1) s += __shfl_down(s, o);
    __shared__ float r[4];
    int lane = threadIdx.x & 63, wid = threadIdx.x >> 6;
    if (lane == 0) r[wid] = s;
    __syncthreads();
    if (threadIdx.x == 0)
        valf[m] = tanhf(r[0] + r[1] + r[2] + r[3] + b[0]);
}

// =============== emit phase (d_out is FLOAT32) ===============
__global__ void emit_f32_k(const float* __restrict__ src, float* __restrict__ out, i64 off, int n)
{
    for (int i = blockIdx.x * blockDim.x + threadIdx.x; i < n; i += gridDim.x * blockDim.x)
        out[off + i] = src[i];
}

__global__ void emit_dup_k(const float* __restrict__ src, float* __restrict__ out,
                           i64 off1, i64 off2, int n)
{
    for (int i = blockIdx.x * blockDim.x + threadIdx.x; i < n; i += gridDim.x * blockDim.x) {
        float v = src[i];
        out[off1 + i] = v;
        out[off2 + i] = v;
    }
}

__global__ void emit_k_k(const int* __restrict__ ki, float* __restrict__ out, i64 off, int n)
{
    for (int i = blockIdx.x * blockDim.x + threadIdx.x; i < n; i += gridDim.x * blockDim.x)
        out[off + i] = (float)ki[i];
}

__global__ void emit_em_k(const float* __restrict__ cm, float* __restrict__ out, i64 off,
                          int D, int SPL, int total)
{
    for (int i = blockIdx.x * blockDim.x + threadIdx.x; i < total; i += gridDim.x * blockDim.x) {
        int c = (i / SPL) % D;
        out[off + i] = cm[c];
    }
}

// =============== guard markers ===============
__global__ void marker_k(float* __restrict__ out, int code)
{
    if (threadIdx.x < 64) out[threadIdx.x] = 3000.f + 100.f * code;
}

__global__ void sentinel_k(float* __restrict__ out)
{
    if (threadIdx.x < 128) out[OUT_VALUE + threadIdx.x] = 2000.0f;
}

// ===================== host launch =====================
extern "C" void kernel_launch(void* const* d_in, const int* in_sizes, int n_in,
                              void* d_out, int out_size, void* d_ws, size_t ws_size,
                              hipStream_t stream)
{
    float* out = (float*)d_out;

    int bad = -1;
    if (out_size != (int)OUT_TOTAL) bad = 0;
    else if (n_in != 41) bad = 1;
    else if (in_sizes[0] != 128 * 18 * 361) bad = 2;
    else if (in_sizes[21] != 11552 * 256) bad = 3;
    if (bad >= 0) { marker_k<<<1, 64, 0, stream>>>(out, bad); return; }

    const float* obs   = (const float*)d_in[0];
    const float* hier  = (const float*)d_in[1];
    const float* c0w   = (const float*)d_in[2];
    const float* bn0g  = (const float*)d_in[4];
    const float* bn0b  = (const float*)d_in[5];
    const float* rb1w  = (const float*)d_in[6];
    const float* rbn1g = (const float*)d_in[8];
    const float* rbn1b = (const float*)d_in[9];
    const float* rb2w  = (const float*)d_in[10];
    const float* rbn2g = (const float*)d_in[12];
    const float* rbn2b = (const float*)d_in[13];
    const float* c2w   = (const float*)d_in[14];
    const float* bn2g  = (const float*)d_in[16];
    const float* bn2b  = (const float*)d_in[17];
    const float* E0    = (const float*)d_in[18];
    const float* E1    = (const float*)d_in[19];
    const float* E2    = (const float*)d_in[20];
    const float* fc1w  = (const float*)d_in[21]; const float* fc1b  = (const float*)d_in[22];
    const float* fc2w  = (const float*)d_in[23]; const float* fc2b  = (const float*)d_in[24];
    const float* h2fw  = (const float*)d_in[25]; const float* h2fb  = (const float*)d_in[26];
    const float* h2f2w = (const float*)d_in[27]; const float* h2f2b = (const float*)d_in[28];
    const float* h2f3w = (const float*)d_in[29]; const float* h2f3b = (const float*)d_in[30];
    const float* h2f4w = (const float*)d_in[31]; const float* h2f4b = (const float*)d_in[32];
    const float* h1f3w = (const float*)d_in[33]; const float* h1f3b = (const float*)d_in[34];
    const float* h1f4w = (const float*)d_in[35]; const float* h1f4b = (const float*)d_in[36];
    const float* polw  = (const float*)d_in[37]; const float* polb  = (const float*)d_in[38];
    const float* valw  = (const float*)d_in[39]; const float* valb  = (const float*)d_in[40];

    float* wsf = (float*)d_ws;

    const size_t NEED_A = (size_t)36732928 * 4;   // MFMA tier: 146.9 MB
    const size_t NEED_C = (size_t)27860992 * 4;   // f32 tier:  111.4 MB
    if (ws_size < NEED_C) {
        sentinel_k<<<1, 128, 0, stream>>>(out);
        return;
    }
    const bool mfma = (ws_size >= NEED_A);

    float* scale = wsf + 0;        float* shift = wsf + 256;
    float* ee0 = wsf + 512;        float* ee1 = wsf + 1024;   float* ee2 = wsf + 1536;
    float* cm0 = wsf + 2048;       float* cm1 = wsf + 2112;   float* cm2 = wsf + 2176;
    int*   k0i = (int*)(wsf + 4096);
    int*   k1i = (int*)(wsf + 50304);
    int*   k2i = (int*)(wsf + 51328);
    float* h1a  = wsf + 53248;
    float* ze1f = wsf + 86016;
    float* zq1f = wsf + 151552;
    float* h2a  = wsf + 217088;
    float* ze2f = wsf + 233472;
    float* zq2f = wsf + 299008;
    float* h2b  = wsf + 364544;
    float* decf = wsf + 380928;
    float* x1f  = wsf + 446464;
    float* h1b  = wsf + 512000;
    float* polf = wsf + 544768;
    float* valf = wsf + 591104;

    float* A   = wsf + 655360;
    float* R   = wsf + 12484608;
    float* C   = wsf + 24313856;
    float* WT  = mfma ? (wsf + 36143104) : (wsf + 27271168);
    float* ze0f = A;
    float* zq0f = wsf + 655360 + 1572864;
    float* dec0 = wsf + 655360 + 3145728;
    float* xf   = wsf + 655360 + 4718592;
    float* part = R;

    short* WT4 = (short*)d_out;   // dead until emit phase

    const int TOT256 = 128 * 256 * 361;
    const int TOT32  = 128 * 32 * 361;

    prep_k<<<4, 512, 0, stream>>>(E0, E1, E2, ee0, ee1, ee2, cm0, cm1, cm2);

    // ---- trunk ----
    wtr_k<<<64, 256, 0, stream>>>(c0w, WT, 256, 18);
    convgemm_k<18><<<dim3(361, 2), 256, 0, stream>>>(obs, WT, A, 256, 0, 256);
    bnstats_k<<<256, 256, 0, stream>>>(A, bn0g, bn0b, scale, shift, 256);
    bn_relu4_k<<<1024, 256, 0, stream>>>((float4*)A, scale, shift, 256, TOT256 / 4);

    if (mfma) {
        for (int i = 0; i < 3; i++) {
            wtr4_k<<<1024, 256, 0, stream>>>(rb1w + (i64)i * 589824, WT4, 256, 256);
            convmfma_k<256><<<dim3(361, 2), 256, 0, stream>>>(A, WT4, R, 256);
            bnstats_k<<<256, 256, 0, stream>>>(R, rbn1g + i * 256, rbn1b + i * 256, scale, shift, 256);
            bn_relu4_k<<<1024, 256, 0, stream>>>((float4*)R, scale, shift, 256, TOT256 / 4);
            wtr4_k<<<1024, 256, 0, stream>>>(rb2w + (i64)i * 589824, WT4, 256, 256);
            convmfma_k<256><<<dim3(361, 2), 256, 0, stream>>>(R, WT4, C, 256);
            bnstats_k<<<256, 256, 0, stream>>>(C, rbn2g + i * 256, rbn2b + i * 256, scale, shift, 256);
            bn_add_relu4_k<<<1024, 256, 0, stream>>>((float4*)A, (const float4*)C, scale, shift, 256, TOT256 / 4);
        }
        wtr4_k<<<1024, 256, 0, stream>>>(c2w, WT4, 256, 32);
        convmfma_k<256><<<dim3(361, 1), 256, 0, stream>>>(A, WT4, C, 32);
        bnstats_k<<<32, 256, 0, stream>>>(C, bn2g, bn2b, scale, shift, 32);
        bn_tanh_ws_k<<<1024, 256, 0, stream>>>(C, scale, shift, ze0f, TOT32);
    } else {
        for (int i = 0; i < 3; i++) {
            wtr_k<<<576, 256, 0, stream>>>(rb1w + (i64)i * 589824, WT, 256, 256);
            convgemm_k<256><<<dim3(361, 2), 256, 0, stream>>>(A, WT, R, 256, 0, 256);
            bnstats_k<<<256, 256, 0, stream>>>(R, rbn1g + i * 256, rbn1b + i * 256, scale, shift, 256);
            bn_relu4_k<<<1024, 256, 0, stream>>>((float4*)R, scale, shift, 256, TOT256 / 4);
            wtr_k<<<576, 256, 0, stream>>>(rb2w + (i64)i * 589824, WT, 256, 256);
            convgemm_k<256><<<dim3(361, 2), 256, 0, stream>>>(R, WT, C, 256, 0, 256);
            bnstats_k<<<256, 256, 0, stream>>>(C, rbn2g + i * 256, rbn2b + i * 256, scale, shift, 256);
            bn_add_relu4_k<<<1024, 256, 0, stream>>>((float4*)A, (const float4*)C, scale, shift, 256, TOT256 / 4);
        }
        wtr_k<<<72, 256, 0, stream>>>(c2w, WT, 32, 256);
        convgemm_k<256><<<dim3(361, 1), 256, 0, stream>>>(A, WT, C, 32, 0, 32);
        bnstats_k<<<32, 256, 0, stream>>>(C, bn2g, bn2b, scale, shift, 32);
        bn_tanh_ws_k<<<1024, 256, 0, stream>>>(C, scale, shift, ze0f, TOT32);
    }

    vq0_k<<<181, 256, 0, stream>>>(ze0f, E0, ee0, zq0f, k0i);

    gemm_part_k<<<dim3(4, 32), 256, 0, stream>>>(ze0f, fc1w, part, 11552, 256, 361);
    combine_k<<<128, 256, 0, stream>>>(part, fc1b, h1a, 128 * 256, 256, 32, 1);
    gemm_part_k<<<dim3(8, 4), 256, 0, stream>>>(h1a, fc2w, part, 256, 512, 64);
    combine_k<<<256, 256, 0, stream>>>(part, fc2b, ze1f, 128 * 512, 512, 4, 2);
    vq64_k<<<4, 256, 0, stream>>>(ze1f, E1, ee1, zq1f, k1i);

    gemm_part_k<<<dim3(2, 8), 256, 0, stream>>>(ze1f, h2fw, part, 512, 128, 64);
    combine_k<<<64, 256, 0, stream>>>(part, h2fb, h2a, 128 * 128, 128, 8, 1);
    gemm_part_k<<<dim3(8, 2), 256, 0, stream>>>(h2a, h2f2w, part, 128, 512, 64);
    combine_k<<<256, 256, 0, stream>>>(part, h2f2b, ze2f, 128 * 512, 512, 2, 2);
    vq64_k<<<4, 256, 0, stream>>>(ze2f, E2, ee2, zq2f, k2i);

    gemm_part_k<<<dim3(2, 8), 256, 0, stream>>>(zq2f, h2f3w, part, 512, 128, 64);
    combine_k<<<64, 256, 0, stream>>>(part, h2f3b, h2b, 128 * 128, 128, 8, 1);
    gemm_part_k<<<dim3(8, 2), 256, 0, stream>>>(h2b, h2f4w, part, 128, 512, 64);
    combine_k<<<256, 256, 0, stream>>>(part, h2f4b, decf, 128 * 512, 512, 2, 2);
    blend_k<<<256, 256, 0, stream>>>(zq1f, decf, hier, 1, x1f, 512, 65536);

    gemm_part_k<<<dim3(4, 8), 256, 0, stream>>>(x1f, h1f3w, part, 512, 256, 64);
    combine_k<<<128, 256, 0, stream>>>(part, h1f3b, h1b, 128 * 256, 256, 8, 1);
    gemm_part_k<<<dim3(181, 2), 256, 0, stream>>>(h1b, h1f4w, part, 256, 11552, 128);
    combine_k<<<1024, 256, 0, stream>>>(part, h1f4b, dec0, TOT32, 11552, 2, 2);
    blend_k<<<1024, 256, 0, stream>>>(zq0f, dec0, hier, 0, xf, 11552, TOT32);

    gemm_part_k<<<dim3(6, 16), 256, 0, stream>>>(xf, polw, part, 11552, 362, 722);
    combine_k<<<256, 256, 0, stream>>>(part, polb, polf, 128 * 362, 362, 16, 0);
    value_k<<<128, 256, 0, stream>>>(xf, valw, valb, valf);

    // ---- emit phase (overwrites WT4 region; sole d_out writers from here) ----
    emit_f32_k<<<128, 256, 0, stream>>>(polf, out, OUT_POLICY, 46336);
    emit_f32_k<<<1, 128, 0, stream>>>(valf, out, OUT_VALUE, 128);
    emit_f32_k<<<1024, 256, 0, stream>>>(ze0f, out, OUT_ZE0, TOT32);
    emit_f32_k<<<256, 256, 0, stream>>>(ze1f, out, OUT_ZE1, 65536);
    emit_f32_k<<<256, 256, 0, stream>>>(ze2f, out, OUT_ZE2, 65536);
    emit_dup_k<<<1024, 256, 0, stream>>>(zq0f, out, OUT_ZQ0, OUT_ZQL0, TOT32);
    emit_dup_k<<<256, 256, 0, stream>>>(zq1f, out, OUT_ZQ1, OUT_ZQL1, 65536);
    emit_dup_k<<<256, 256, 0, stream>>>(zq2f, out, OUT_ZQ2, OUT_ZQL2, 65536);
    emit_k_k<<<181, 256, 0, stream>>>(k0i, out, OUT_K0, 46208);
    emit_k_k<<<4, 256, 0, stream>>>(k1i, out, OUT_K1, 1024);
    emit_k_k<<<4, 256, 0, stream>>>(k2i, out, OUT_K2, 1024);
    emit_em_k<<<1024, 256, 0, stream>>>(cm0, out, OUT_EM0, 32, 361, TOT32);
    emit_em_k<<<256, 256, 0, stream>>>(cm1, out, OUT_EM1, 64, 8, 65536);
    emit_em_k<<<256, 256, 0, stream>>>(cm2, out, OUT_EM2, 64, 8, 65536);
}

// Round 17
// 3269.968 us; speedup vs baseline: 1.2225x; 1.2225x over previous
//
#include <hip/hip_runtime.h>
#include <hip/hip_bf16.h>

typedef long long i64;
typedef __attribute__((ext_vector_type(8))) short bf16x8;
typedef __attribute__((ext_vector_type(4))) float f32x4;

// ---- output element offsets (FLOAT32 elements — d_out is float*) ----
static constexpr i64 OUT_POLICY = 0;
static constexpr i64 OUT_VALUE  = 46336;
static constexpr i64 OUT_ZE0    = 46464;
static constexpr i64 OUT_ZE1    = 1525120;
static constexpr i64 OUT_ZE2    = 1590656;
static constexpr i64 OUT_ZQ0    = 1656192;
static constexpr i64 OUT_ZQ1    = 3134848;
static constexpr i64 OUT_ZQ2    = 3200384;
static constexpr i64 OUT_K0     = 3265920;
static constexpr i64 OUT_K1     = 3312128;
static constexpr i64 OUT_K2     = 3313152;
static constexpr i64 OUT_ZQL0   = 3314176;
static constexpr i64 OUT_ZQL1   = 4792832;
static constexpr i64 OUT_ZQL2   = 4858368;
static constexpr i64 OUT_EM0    = 4923904;
static constexpr i64 OUT_EM1    = 6402560;
static constexpr i64 OUT_EM2    = 6468096;
static constexpr i64 OUT_TOTAL  = 6533632;

__device__ __forceinline__ short bf16_hi(float v, float* back)
{
    unsigned b = __float_as_uint(v);
    unsigned hb = (b + 0x8000u) & 0xFFFF0000u;
    *back = __uint_as_float(hb);
    return (short)(hb >> 16);
}
__device__ __forceinline__ short bf16_of(float v)
{
    return (short)((__float_as_uint(v) + 0x8000u) >> 16);
}

// =============== weight transpose (f32 path) ===============
__global__ void wtr_k(const float* __restrict__ w, float* __restrict__ wt,
                      int COUT, int CIN)
{
    int total = COUT * CIN * 9;
    for (int idx = blockIdx.x * blockDim.x + threadIdx.x; idx < total;
         idx += gridDim.x * blockDim.x) {
        int co = idx / (CIN * 9);
        int r  = idx - co * CIN * 9;
        int ci = r / 9;
        int tap = r - ci * 9;
        wt[((i64)tap * CIN + ci) * COUT + co] = w[idx];
    }
}

// =============== MFMA weight prep: swizzled bf16 hi/lo tiles ===============
__global__ void wtr4_k(const float* __restrict__ w, short* __restrict__ wt4,
                       int CIN, int COUT)
{
    int NC = CIN / 32;
    int total = NC * 9 * 2 * 8192;
    for (int idx = blockIdx.x * blockDim.x + threadIdx.x; idx < total;
         idx += gridDim.x * blockDim.x) {
        int tile = idx >> 13;
        int pos  = idx & 8191;
        int row   = pos >> 6;
        int sslot = (pos >> 3) & 7;
        int r     = pos & 7;
        int slot  = sslot ^ (row & 7);
        int k2    = slot * 8 + r;
        int ct = tile & 1;
        int s  = tile >> 1;
        int c  = s / 9, t = s - c * 9;
        int co = ct * 128 + row;
        int ci = c * 32 + (k2 & 31);
        short outv = 0;
        if (co < COUT) {
            float v = w[((i64)co * CIN + ci) * 9 + t];
            float hf;
            short hs = bf16_hi(v, &hf);
            outv = (k2 < 32) ? hs : bf16_of(v - hf);
        }
        wt4[idx] = outv;
    }
}

// =============== MFMA conv 3x3: implicit GEMM, 4-term bf16 split ===============
// Round-13 proven body (A from global inside compute, Bt-only 32KB LDS dbuf)
// + XCD-bijective block swizzle ONLY (m204; zero VGPR cost, same math).
template<int CIN>
__global__ __launch_bounds__(256)
void convmfma_k(const float* __restrict__ X, const short* __restrict__ WT4,
                float* __restrict__ Y, int coutT)
{
    constexpr int NC = CIN / 32;
    constexpr int NS = NC * 9;
    __shared__ short Bt[2][8192];
    const int tid  = threadIdx.x;
    const int lane = tid & 63;
    const int w    = tid >> 6;
    const int wco  = (w & 1) * 64;
    const int wsp  = (w >> 1) * 64;

    // XCD-bijective swizzle of the col-tile index (nwg=361, 361%8=1)
    const int q8 = (int)gridDim.x >> 3;
    const int r8 = (int)gridDim.x & 7;
    const int xcd = (int)blockIdx.x & 7;
    const int boff = (int)blockIdx.x >> 3;
    const int bcol = (xcd < r8) ? (xcd * (q8 + 1) + boff)
                                : (r8 * (q8 + 1) + (xcd - r8) * q8 + boff);
    const int col0 = bcol * 128;
    const int ct   = blockIdx.y;
    const int co0  = ct * 128;

    const int spS = tid & 127;
    const int cig = tid >> 7;
    const int colS = col0 + spS;
    const int nS = colS / 361;
    const int sS = colS - nS * 361;
    const int yS = sS / 19, xS = sS - yS * 19;
    const float* Xb = X + (i64)nS * CIN * 361 + sS;

    float xv[16];

#define B_LOAD(S)                                                               \
    {                                                                           \
        const int c_ = (S) / 9, t_ = (S) - c_ * 9;                              \
        const int ky_ = t_ / 3, kx_ = t_ - ky_ * 3;                             \
        const bool v_ = (yS + ky_ >= 1) & (yS + ky_ <= 19) &                    \
                        (xS + kx_ >= 1) & (xS + kx_ <= 19);                     \
        const float* xp_ = Xb + (i64)(c_ * 32 + cig * 16) * 361                 \
                              + (ky_ - 1) * 19 + (kx_ - 1);                     \
        _Pragma("unroll")                                                       \
        for (int j = 0; j < 16; j++) xv[j] = v_ ? xp_[(i64)j * 361] : 0.f;      \
    }

#define B_WRITE(BUF)                                                            \
    {                                                                           \
        bf16x8 h0, h1, l0, l1;                                                  \
        _Pragma("unroll")                                                       \
        for (int j = 0; j < 8; j++) {                                           \
            float hf;                                                           \
            short hs = bf16_hi(xv[j], &hf);                                     \
            h0[j] = hs; l0[j] = bf16_of(xv[j] - hf);                            \
        }                                                                       \
        _Pragma("unroll")                                                       \
        for (int j = 0; j < 8; j++) {                                           \
            float hf;                                                           \
            short hs = bf16_hi(xv[8 + j], &hf);                                 \
            h1[j] = hs; l1[j] = bf16_of(xv[8 + j] - hf);                        \
        }                                                                       \
        short* bp = &Bt[BUF][spS << 6];                                         \
        const int sw = spS & 7;                                                 \
        *(bf16x8*)(bp + (((cig * 2 + 0) ^ sw) << 3)) = h0;                      \
        *(bf16x8*)(bp + (((cig * 2 + 1) ^ sw) << 3)) = h1;                      \
        *(bf16x8*)(bp + (((4 + cig * 2 + 0) ^ sw) << 3)) = l0;                  \
        *(bf16x8*)(bp + (((4 + cig * 2 + 1) ^ sw) << 3)) = l1;                  \
    }

    f32x4 acc[4][4];
#pragma unroll
    for (int i = 0; i < 4; i++)
#pragma unroll
        for (int j = 0; j < 4; j++) acc[i][j] = (f32x4){0.f, 0.f, 0.f, 0.f};

    B_LOAD(0)
    B_WRITE(0)
    int cur = 0;
    for (int s = 0; s < NS; s++) {
        __syncthreads();                  // buf[cur] ready
        if (s + 1 < NS) B_LOAD(s + 1)     // next-tile globals in flight
        {
            const short* tb = WT4 + ((i64)(s * 2 + ct) << 13);
            bf16x8 afr[2][4];
#pragma unroll
            for (int ha = 0; ha < 2; ha++)
#pragma unroll
                for (int fa = 0; fa < 4; fa++) {
                    int row = wco + fa * 16 + (lane & 15);
                    int slot = ha * 4 + (lane >> 4);
                    afr[ha][fa] = *(const bf16x8*)(tb + (row << 6) + (((slot ^ (row & 7))) << 3));
                }
            bf16x8 bfr[2][4];
#pragma unroll
            for (int hb = 0; hb < 2; hb++)
#pragma unroll
                for (int fb = 0; fb < 4; fb++) {
                    int row = wsp + fb * 16 + (lane & 15);
                    int slot = hb * 4 + (lane >> 4);
                    bfr[hb][fb] = *(const bf16x8*)&Bt[cur][(row << 6) + (((slot ^ (row & 7))) << 3)];
                }
#pragma unroll
            for (int ha = 0; ha < 2; ha++)
#pragma unroll
                for (int fa = 0; fa < 4; fa++) {
                    bf16x8 af = afr[ha][fa];
#pragma unroll
                    for (int hb = 0; hb < 2; hb++)
#pragma unroll
                        for (int fb = 0; fb < 4; fb++)
                            acc[fa][fb] = __builtin_amdgcn_mfma_f32_16x16x32_bf16(
                                af, bfr[hb][fb], acc[fa][fb], 0, 0, 0);
                }
        }
        if (s + 1 < NS) B_WRITE(cur ^ 1)
        cur ^= 1;
    }
#undef B_LOAD
#undef B_WRITE

#pragma unroll
    for (int fb = 0; fb < 4; fb++) {
        int col = col0 + wsp + fb * 16 + (lane & 15);
        int nT = col / 361, sT = col - nT * 361;
        float* yp = Y + ((i64)nT * coutT + co0 + wco) * 361 + sT;
#pragma unroll
        for (int fa = 0; fa < 4; fa++)
#pragma unroll
            for (int r = 0; r < 4; r++) {
                int m = fa * 16 + (lane >> 4) * 4 + r;
                if (co0 + wco + m < coutT) yp[(i64)m * 361] = acc[fa][fb][r];
            }
    }
}

// =============== f32 conv (CIN=18 first conv + fallback) ===============
template<int CIN>
__global__ __launch_bounds__(256)
void convgemm_k(const float* __restrict__ X, const float* __restrict__ wt,
                float* __restrict__ Y, int wtW, int coW0, int coutT)
{
    constexpr int NCB = (CIN + 15) / 16;
    constexpr int NS  = 9 * NCB;
    __shared__ float Ws[2][16][128];
    __shared__ float Bs[2][16][128];
    const int tid  = threadIdx.x;
    const int col0 = blockIdx.x * 128;
    const int co0  = blockIdx.y * 128;
    const int tn = tid & 15;
    const int tm = (tid >> 4) & 15;
    const int kkS  = tid >> 5;
    const int cS0  = (tid & 31) * 4;

    int y_[4], x_[4];
    const float* Xb[4];
#pragma unroll
    for (int j = 0; j < 4; j++) {
        int colj = col0 + cS0 + j;
        int nj = colj / 361;
        int sj = colj - nj * 361;
        y_[j] = sj / 19;
        x_[j] = sj - y_[j] * 19;
        Xb[j] = X + ((i64)nj * CIN) * 361 + sj;
    }

    float4 wA, wB, bA, bB;

#define STAGE(S)                                                               \
    {                                                                          \
        const int tap_ = (S) / NCB, cb_ = ((S) % NCB) * 16;                    \
        const int ky_ = tap_ / 3, kx_ = tap_ - ky_ * 3;                        \
        const int doff_ = (ky_ - 1) * 19 + (kx_ - 1);                          \
        const int ci0_ = cb_ + kkS, ci1_ = ci0_ + 8;                           \
        const float* wr_ = wt + ((i64)(tap_ * CIN) + ci0_) * wtW               \
                              + coW0 + co0 + cS0;                              \
        const bool wok_ = (coW0 + co0 + cS0) < wtW;                            \
        wA = (wok_ && ci0_ < CIN) ? *(const float4*)wr_                        \
                                  : float4{0.f, 0.f, 0.f, 0.f};                \
        wB = (wok_ && ci1_ < CIN) ? *(const float4*)(wr_ + (i64)8 * wtW)       \
                                  : float4{0.f, 0.f, 0.f, 0.f};                \
        bool v0_ = (y_[0]+ky_>=1)&(y_[0]+ky_<=19)&(x_[0]+kx_>=1)&(x_[0]+kx_<=19); \
        bool v1_ = (y_[1]+ky_>=1)&(y_[1]+ky_<=19)&(x_[1]+kx_>=1)&(x_[1]+kx_<=19); \
        bool v2_ = (y_[2]+ky_>=1)&(y_[2]+ky_<=19)&(x_[2]+kx_>=1)&(x_[2]+kx_<=19); \
        bool v3_ = (y_[3]+ky_>=1)&(y_[3]+ky_<=19)&(x_[3]+kx_>=1)&(x_[3]+kx_<=19); \
        bA.x = (v0_ && ci0_ < CIN) ? Xb[0][(i64)ci0_ * 361 + doff_] : 0.f;     \
        bA.y = (v1_ && ci0_ < CIN) ? Xb[1][(i64)ci0_ * 361 + doff_] : 0.f;     \
        bA.z = (v2_ && ci0_ < CIN) ? Xb[2][(i64)ci0_ * 361 + doff_] : 0.f;     \
        bA.w = (v3_ && ci0_ < CIN) ? Xb[3][(i64)ci0_ * 361 + doff_] : 0.f;     \
        bB.x = (v0_ && ci1_ < CIN) ? Xb[0][(i64)ci1_ * 361 + doff_] : 0.f;     \
        bB.y = (v1_ && ci1_ < CIN) ? Xb[1][(i64)ci1_ * 361 + doff_] : 0.f;     \
        bB.z = (v2_ && ci1_ < CIN) ? Xb[2][(i64)ci1_ * 361 + doff_] : 0.f;     \
        bB.w = (v3_ && ci1_ < CIN) ? Xb[3][(i64)ci1_ * 361 + doff_] : 0.f;     \
    }

#define WRITE(BUF)                                                             \
    {                                                                          \
        *(float4*)&Ws[BUF][kkS    ][cS0] = wA;                                 \
        *(float4*)&Ws[BUF][kkS + 8][cS0] = wB;                                 \
        *(float4*)&Bs[BUF][kkS    ][cS0] = bA;                                 \
        *(float4*)&Bs[BUF][kkS + 8][cS0] = bB;                                 \
    }

    float acc[8][8];
#pragma unroll
    for (int i = 0; i < 8; i++)
#pragma unroll
        for (int j = 0; j < 8; j++) acc[i][j] = 0.f;

    STAGE(0)
    WRITE(0)
    int cur = 0;
    for (int s = 0; s < NS; s++) {
        __syncthreads();
        if (s + 1 < NS) STAGE(s + 1)
#pragma unroll
        for (int kk = 0; kk < 16; kk++) {
            const float4 w0 = *(const float4*)&Ws[cur][kk][tm * 4];
            const float4 w1 = *(const float4*)&Ws[cur][kk][tm * 4 + 64];
            const float4 b0 = *(const float4*)&Bs[cur][kk][tn * 4];
            const float4 b1 = *(const float4*)&Bs[cur][kk][tn * 4 + 64];
            float wv[8] = {w0.x, w0.y, w0.z, w0.w, w1.x, w1.y, w1.z, w1.w};
            float bv[8] = {b0.x, b0.y, b0.z, b0.w, b1.x, b1.y, b1.z, b1.w};
#pragma unroll
            for (int wi = 0; wi < 8; wi++)
#pragma unroll
                for (int bj = 0; bj < 8; bj++)
                    acc[wi][bj] = fmaf(wv[wi], bv[bj], acc[wi][bj]);
        }
        if (s + 1 < NS) WRITE(cur ^ 1)
        cur ^= 1;
    }
#undef STAGE
#undef WRITE

#pragma unroll
    for (int bj = 0; bj < 8; bj++) {
        int lc = (bj < 4) ? (tn * 4 + bj) : (64 + tn * 4 + bj - 4);
        int colT = col0 + lc;
        int nT = colT / 361;
        int sT = colT - nT * 361;
        float* yp = Y + ((i64)nT * coutT + co0) * 361 + sT;
#pragma unroll
        for (int wi = 0; wi < 8; wi++) {
            int co = (wi < 4) ? (tm * 4 + wi) : (64 + tm * 4 + wi - 4);
            if (co0 + co < coutT) yp[(i64)co * 361] = acc[wi][bj];
        }
    }
}

// =============== BN batch-stats -> scale/shift ===============
__global__ __launch_bounds__(256)
void bnstats_k(const float* __restrict__ x, const float* __restrict__ g,
               const float* __restrict__ b, float* __restrict__ scale,
               float* __restrict__ shift, int C)
{
    const int c = blockIdx.x;
    float s = 0.f, s2 = 0.f;
    for (int n = 0; n < 128; n++) {
        const float* p = x + ((i64)n * C + c) * 361;
        for (int i = threadIdx.x; i < 361; i += 256) {
            float v = p[i]; s += v; s2 += v * v;
        }
    }
    __shared__ float rs[4], rq[4];
    for (int o = 32; o > 0; o >>= 1) { s += __shfl_down(s, o); s2 += __shfl_down(s2, o); }
    int lane = threadIdx.x & 63, wid = threadIdx.x >> 6;
    if (lane == 0) { rs[wid] = s; rq[wid] = s2; }
    __syncthreads();
    if (threadIdx.x == 0) {
        float S = rs[0] + rs[1] + rs[2] + rs[3];
        float Q = rq[0] + rq[1] + rq[2] + rq[3];
        const float inv = 1.f / 46208.f;
        float m  = S * inv;
        float var = Q * inv - m * m;
        float sc = g[c] * rsqrtf(var + 1e-5f);
        scale[c] = sc;
        shift[c] = b[c] - m * sc;
    }
}

// =============== BN apply (vectorized) ===============
__global__ void bn_relu4_k(float4* __restrict__ x, const float* __restrict__ scale,
                           const float* __restrict__ shift, int C, int total4)
{
    for (int i = blockIdx.x * blockDim.x + threadIdx.x; i < total4; i += gridDim.x * blockDim.x) {
        float4 v = x[i];
        int e = i * 4;
        int c0 = (e / 361) % C, c1 = ((e + 1) / 361) % C;
        int c2 = ((e + 2) / 361) % C, c3 = ((e + 3) / 361) % C;
        v.x = fmaf(v.x, scale[c0], shift[c0]); v.x = v.x > 0.f ? v.x : 0.f;
        v.y = fmaf(v.y, scale[c1], shift[c1]); v.y = v.y > 0.f ? v.y : 0.f;
        v.z = fmaf(v.z, scale[c2], shift[c2]); v.z = v.z > 0.f ? v.z : 0.f;
        v.w = fmaf(v.w, scale[c3], shift[c3]); v.w = v.w > 0.f ? v.w : 0.f;
        x[i] = v;
    }
}

__global__ void bn_add_relu4_k(float4* __restrict__ xa, const float4* __restrict__ xc,
                               const float* __restrict__ scale, const float* __restrict__ shift,
                               int C, int total4)
{
    for (int i = blockIdx.x * blockDim.x + threadIdx.x; i < total4; i += gridDim.x * blockDim.x) {
        float4 a = xa[i], c = xc[i];
        int e = i * 4;
        int c0 = (e / 361) % C, c1 = ((e + 1) / 361) % C;
        int c2 = ((e + 2) / 361) % C, c3 = ((e + 3) / 361) % C;
        a.x += fmaf(c.x, scale[c0], shift[c0]); a.x = a.x > 0.f ? a.x : 0.f;
        a.y += fmaf(c.y, scale[c1], shift[c1]); a.y = a.y > 0.f ? a.y : 0.f;
        a.z += fmaf(c.z, scale[c2], shift[c2]); a.z = a.z > 0.f ? a.z : 0.f;
        a.w += fmaf(c.w, scale[c3], shift[c3]); a.w = a.w > 0.f ? a.w : 0.f;
        xa[i] = a;
    }
}

__global__ void bn_tanh_ws_k(const float* __restrict__ x, const float* __restrict__ scale,
                             const float* __restrict__ shift, float* __restrict__ zf, int total)
{
    for (int i = blockIdx.x * blockDim.x + threadIdx.x; i < total; i += gridDim.x * blockDim.x) {
        int c = (i / 361) & 31;
        zf[i] = tanhf(fmaf(x[i], scale[c], shift[c]));
    }
}

// =============== codebook prep ===============
__global__ void prep_k(const float* __restrict__ E0, const float* __restrict__ E1,
                       const float* __restrict__ E2,
                       float* __restrict__ ee0, float* __restrict__ ee1, float* __restrict__ ee2,
                       float* __restrict__ cm0, float* __restrict__ cm1, float* __restrict__ cm2)
{
    int t = threadIdx.x;
    if (blockIdx.x == 0) {
        float s = 0.f; const float* e = E0 + (i64)t * 32;
        for (int d = 0; d < 32; d++) s += e[d] * e[d];
        ee0[t] = s;
    } else if (blockIdx.x == 1) {
        float s = 0.f; const float* e = E1 + (i64)t * 64;
        for (int d = 0; d < 64; d++) s += e[d] * e[d];
        ee1[t] = s;
    } else if (blockIdx.x == 2) {
        float s = 0.f; const float* e = E2 + (i64)t * 64;
        for (int d = 0; d < 64; d++) s += e[d] * e[d];
        ee2[t] = s;
    } else {
        if (t < 32) {
            float s = 0.f; for (int k = 0; k < 512; k++) s += E0[k * 32 + t];
            cm0[t] = s * (1.f / 512.f);
        } else if (t >= 64 && t < 128) {
            int d = t - 64; float s = 0.f; for (int k = 0; k < 512; k++) s += E1[k * 64 + d];
            cm1[d] = s * (1.f / 512.f);
        } else if (t >= 128 && t < 192) {
            int d = t - 128; float s = 0.f; for (int k = 0; k < 512; k++) s += E2[k * 64 + d];
            cm2[d] = s * (1.f / 512.f);
        }
    }
}

// =============== VQ kernels ===============
__global__ __launch_bounds__(256)
void vq0_k(const float* __restrict__ z, const float* __restrict__ E,
           const float* __restrict__ ee, float* __restrict__ zqf, int* __restrict__ ki)
{
    __shared__ float Es[256 * 32];
    int row = blockIdx.x * 256 + threadIdx.x;
    const bool live = row < 46208;
    const float* zp = z + (i64)(live ? row : 0) * 32;
    float zv[32]; float zz = 0.f;
#pragma unroll
    for (int d = 0; d < 32; d++) { float v = zp[d]; zv[d] = v; zz += v * v; }
    float best = 3.4e38f; int bk = 0;
    for (int h = 0; h < 2; h++) {
        __syncthreads();
        for (int i = threadIdx.x; i < 256 * 32; i += 256) Es[i] = E[h * 8192 + i];
        __syncthreads();
        for (int k = 0; k < 256; k++) {
            const float* e = Es + k * 32;
            float dot = 0.f;
#pragma unroll
            for (int d = 0; d < 32; d++) dot = fmaf(zv[d], e[d], dot);
            float dist = (zz + ee[h * 256 + k]) - 2.f * dot;
            if (dist < best) { best = dist; bk = h * 256 + k; }
        }
    }
    if (live) {
        ki[row] = bk;
        const float* eb = E + (i64)bk * 32;
#pragma unroll
        for (int d = 0; d < 32; d++) zqf[(i64)row * 32 + d] = eb[d];
    }
}

__global__ __launch_bounds__(256)
void vq64_k(const float* __restrict__ z, const float* __restrict__ E,
            const float* __restrict__ ee, float* __restrict__ zqf, int* __restrict__ ki)
{
    __shared__ float Es[128 * 64];
    int row = blockIdx.x * 256 + threadIdx.x;
    const float* zp = z + (i64)row * 64;
    float zv[64]; float zz = 0.f;
#pragma unroll
    for (int d = 0; d < 64; d++) { float v = zp[d]; zv[d] = v; zz += v * v; }
    float best = 3.4e38f; int bk = 0;
    for (int h = 0; h < 4; h++) {
        __syncthreads();
        for (int i = threadIdx.x; i < 128 * 64; i += 256) Es[i] = E[(i64)h * 8192 + i];
        __syncthreads();
        for (int k = 0; k < 128; k++) {
            const float* e = Es + k * 64;
            float dot = 0.f;
#pragma unroll
            for (int d = 0; d < 64; d++) dot = fmaf(zv[d], e[d], dot);
            float dist = (zz + ee[h * 128 + k]) - 2.f * dot;
            if (dist < best) { best = dist; bk = h * 128 + k; }
        }
    }
    ki[row] = bk;
    const float* eb = E + (i64)bk * 64;
#pragma unroll
    for (int d = 0; d < 64; d++) zqf[(i64)row * 64 + d] = eb[d];
}

// =============== split-K GEMM ===============
__global__ __launch_bounds__(256)
void gemm_part_k(const float* __restrict__ A, const float* __restrict__ W,
                 float* __restrict__ part, int K, int N, int kchunk)
{
    __shared__ float As[128][17];
    __shared__ float Ws[16][64];
    const int n0 = blockIdx.x * 64;
    const int ks = blockIdx.y;
    const int kb0  = ks * kchunk;
    const int kend = min(K, kb0 + kchunk);
    const int tid = threadIdx.x;
    const int tn = tid & 15, tm = tid >> 4;
    float acc[8][4];
#pragma unroll
    for (int i = 0; i < 8; i++)
#pragma unroll
        for (int j = 0; j < 4; j++) acc[i][j] = 0.f;

    for (int kb = kb0; kb < kend; kb += 16) {
        __syncthreads();
        for (int i = tid; i < 2048; i += 256) {
            int m = i >> 4, kk = i & 15;
            int k = kb + kk;
            As[m][kk] = (k < kend) ? A[(i64)m * K + k] : 0.f;
        }
        for (int i = tid; i < 1024; i += 256) {
            int kk = i >> 6, nl = i & 63;
            int k = kb + kk, n = n0 + nl;
            Ws[kk][nl] = (k < kend && n < N) ? W[(i64)k * N + n] : 0.f;
        }
        __syncthreads();
#pragma unroll
        for (int kk = 0; kk < 16; kk++) {
            float av[8], wv[4];
#pragma unroll
            for (int i = 0; i < 8; i++) av[i] = As[tm * 8 + i][kk];
#pragma unroll
            for (int j = 0; j < 4; j++) wv[j] = Ws[kk][tn * 4 + j];
#pragma unroll
            for (int i = 0; i < 8; i++)
#pragma unroll
                for (int j = 0; j < 4; j++) acc[i][j] = fmaf(av[i], wv[j], acc[i][j]);
        }
    }
#pragma unroll
    for (int i = 0; i < 8; i++) {
        int m = tm * 8 + i;
#pragma unroll
        for (int j = 0; j < 4; j++) {
            int n = n0 + tn * 4 + j;
            if (n < N) part[((i64)ks * 128 + m) * N + n] = acc[i][j];
        }
    }
}

__global__ void combine_k(const float* __restrict__ part, const float* __restrict__ bias,
                          float* __restrict__ of, int MN, int N, int ksplit, int act)
{
    for (int i = blockIdx.x * blockDim.x + threadIdx.x; i < MN; i += gridDim.x * blockDim.x) {
        float s = 0.f;
        for (int t = 0; t < ksplit; t++) s += part[(i64)t * MN + i];
        s += bias[i % N];
        if (act == 1) s = s > 0.f ? s : 0.f;
        else if (act == 2) s = tanhf(s);
        of[i] = s;
    }
}

__global__ void blend_k(const float* __restrict__ q, const float* __restrict__ d,
                        const float* __restrict__ hu, int col, float* __restrict__ o,
                        int per_b, int total)
{
    for (int i = blockIdx.x * blockDim.x + threadIdx.x; i < total; i += gridDim.x * blockDim.x) {
        float u = hu[(i / per_b) * 2 + col];
        o[i] = u * q[i] + (1.f - u) * d[i];
    }
}

__global__ __launch_bounds__(256)
void value_k(const float* __restrict__ x, const float* __restrict__ w,
             const float* __restrict__ b, float* __restrict__ valf)
{
    int m = blockIdx.x;
    float s = 0.f;
    const float* xp = x + (i64)m * 11552;
    for (int k = threadIdx.x; k < 11552; k += 256) s = fmaf(xp[k], w[k], s);
    for (int o = 32; o > 0; o >>= 1) s += __shfl_down(s, o);
    __shared__ float r[4];
    int lane = threadIdx.x & 63, wid = threadIdx.x >> 6;
    if (lane == 0) r[wid] = s;
    __syncthreads();
    if (threadIdx.x == 0)
        valf[m] = tanhf(r[0] + r[1] + r[2] + r[3] + b[0]);
}

// =============== emit phase (d_out is FLOAT32) ===============
__global__ void emit_f32_k(const float* __restrict__ src, float* __restrict__ out, i64 off, int n)
{
    for (int i = blockIdx.x * blockDim.x + threadIdx.x; i < n; i += gridDim.x * blockDim.x)
        out[off + i] = src[i];
}

__global__ void emit_dup_k(const float* __restrict__ src, float* __restrict__ out,
                           i64 off1, i64 off2, int n)
{
    for (int i = blockIdx.x * blockDim.x + threadIdx.x; i < n; i += gridDim.x * blockDim.x) {
        float v = src[i];
        out[off1 + i] = v;
        out[off2 + i] = v;
    }
}

__global__ void emit_k_k(const int* __restrict__ ki, float* __restrict__ out, i64 off, int n)
{
    for (int i = blockIdx.x * blockDim.x + threadIdx.x; i < n; i += gridDim.x * blockDim.x)
        out[off + i] = (float)ki[i];
}

__global__ void emit_em_k(const float* __restrict__ cm, float* __restrict__ out, i64 off,
                          int D, int SPL, int total)
{
    for (int i = blockIdx.x * blockDim.x + threadIdx.x; i < total; i += gridDim.x * blockDim.x) {
        int c = (i / SPL) % D;
        out[off + i] = cm[c];
    }
}

// =============== guard markers ===============
__global__ void marker_k(float* __restrict__ out, int code)
{
    if (threadIdx.x < 64) out[threadIdx.x] = 3000.f + 100.f * code;
}

__global__ void sentinel_k(float* __restrict__ out)
{
    if (threadIdx.x < 128) out[OUT_VALUE + threadIdx.x] = 2000.0f;
}

// ===================== host launch =====================
extern "C" void kernel_launch(void* const* d_in, const int* in_sizes, int n_in,
                              void* d_out, int out_size, void* d_ws, size_t ws_size,
                              hipStream_t stream)
{
    float* out = (float*)d_out;

    int bad = -1;
    if (out_size != (int)OUT_TOTAL) bad = 0;
    else if (n_in != 41) bad = 1;
    else if (in_sizes[0] != 128 * 18 * 361) bad = 2;
    else if (in_sizes[21] != 11552 * 256) bad = 3;
    if (bad >= 0) { marker_k<<<1, 64, 0, stream>>>(out, bad); return; }

    const float* obs   = (const float*)d_in[0];
    const float* hier  = (const float*)d_in[1];
    const float* c0w   = (const float*)d_in[2];
    const float* bn0g  = (const float*)d_in[4];
    const float* bn0b  = (const float*)d_in[5];
    const float* rb1w  = (const float*)d_in[6];
    const float* rbn1g = (const float*)d_in[8];
    const float* rbn1b = (const float*)d_in[9];
    const float* rb2w  = (const float*)d_in[10];
    const float* rbn2g = (const float*)d_in[12];
    const float* rbn2b = (const float*)d_in[13];
    const float* c2w   = (const float*)d_in[14];
    const float* bn2g  = (const float*)d_in[16];
    const float* bn2b  = (const float*)d_in[17];
    const float* E0    = (const float*)d_in[18];
    const float* E1    = (const float*)d_in[19];
    const float* E2    = (const float*)d_in[20];
    const float* fc1w  = (const float*)d_in[21]; const float* fc1b  = (const float*)d_in[22];
    const float* fc2w  = (const float*)d_in[23]; const float* fc2b  = (const float*)d_in[24];
    const float* h2fw  = (const float*)d_in[25]; const float* h2fb  = (const float*)d_in[26];
    const float* h2f2w = (const float*)d_in[27]; const float* h2f2b = (const float*)d_in[28];
    const float* h2f3w = (const float*)d_in[29]; const float* h2f3b = (const float*)d_in[30];
    const float* h2f4w = (const float*)d_in[31]; const float* h2f4b = (const float*)d_in[32];
    const float* h1f3w = (const float*)d_in[33]; const float* h1f3b = (const float*)d_in[34];
    const float* h1f4w = (const float*)d_in[35]; const float* h1f4b = (const float*)d_in[36];
    const float* polw  = (const float*)d_in[37]; const float* polb  = (const float*)d_in[38];
    const float* valw  = (const float*)d_in[39]; const float* valb  = (const float*)d_in[40];

    float* wsf = (float*)d_ws;

    const size_t NEED_A = (size_t)36732928 * 4;   // MFMA tier: 146.9 MB
    const size_t NEED_C = (size_t)27860992 * 4;   // f32 tier:  111.4 MB
    if (ws_size < NEED_C) {
        sentinel_k<<<1, 128, 0, stream>>>(out);
        return;
    }
    const bool mfma = (ws_size >= NEED_A);

    float* scale = wsf + 0;        float* shift = wsf + 256;
    float* ee0 = wsf + 512;        float* ee1 = wsf + 1024;   float* ee2 = wsf + 1536;
    float* cm0 = wsf + 2048;       float* cm1 = wsf + 2112;   float* cm2 = wsf + 2176;
    int*   k0i = (int*)(wsf + 4096);
    int*   k1i = (int*)(wsf + 50304);
    int*   k2i = (int*)(wsf + 51328);
    float* h1a  = wsf + 53248;
    float* ze1f = wsf + 86016;
    float* zq1f = wsf + 151552;
    float* h2a  = wsf + 217088;
    float* ze2f = wsf + 233472;
    float* zq2f = wsf + 299008;
    float* h2b  = wsf + 364544;
    float* decf = wsf + 380928;
    float* x1f  = wsf + 446464;
    float* h1b  = wsf + 512000;
    float* polf = wsf + 544768;
    float* valf = wsf + 591104;

    float* A   = wsf + 655360;
    float* R   = wsf + 12484608;
    float* C   = wsf + 24313856;
    float* WT  = mfma ? (wsf + 36143104) : (wsf + 27271168);
    float* ze0f = A;
    float* zq0f = wsf + 655360 + 1572864;
    float* dec0 = wsf + 655360 + 3145728;
    float* xf   = wsf + 655360 + 4718592;
    float* part = R;

    short* WT4 = (short*)d_out;   // dead until emit phase

    const int TOT256 = 128 * 256 * 361;
    const int TOT32  = 128 * 32 * 361;

    prep_k<<<4, 512, 0, stream>>>(E0, E1, E2, ee0, ee1, ee2, cm0, cm1, cm2);

    // ---- trunk ----
    wtr_k<<<64, 256, 0, stream>>>(c0w, WT, 256, 18);
    convgemm_k<18><<<dim3(361, 2), 256, 0, stream>>>(obs, WT, A, 256, 0, 256);
    bnstats_k<<<256, 256, 0, stream>>>(A, bn0g, bn0b, scale, shift, 256);
    bn_relu4_k<<<1024, 256, 0, stream>>>((float4*)A, scale, shift, 256, TOT256 / 4);

    if (mfma) {
        for (int i = 0; i < 3; i++) {
            wtr4_k<<<1024, 256, 0, stream>>>(rb1w + (i64)i * 589824, WT4, 256, 256);
            convmfma_k<256><<<dim3(361, 2), 256, 0, stream>>>(A, WT4, R, 256);
            bnstats_k<<<256, 256, 0, stream>>>(R, rbn1g + i * 256, rbn1b + i * 256, scale, shift, 256);
            bn_relu4_k<<<1024, 256, 0, stream>>>((float4*)R, scale, shift, 256, TOT256 / 4);
            wtr4_k<<<1024, 256, 0, stream>>>(rb2w + (i64)i * 589824, WT4, 256, 256);
            convmfma_k<256><<<dim3(361, 2), 256, 0, stream>>>(R, WT4, C, 256);
            bnstats_k<<<256, 256, 0, stream>>>(C, rbn2g + i * 256, rbn2b + i * 256, scale, shift, 256);
            bn_add_relu4_k<<<1024, 256, 0, stream>>>((float4*)A, (const float4*)C, scale, shift, 256, TOT256 / 4);
        }
        wtr4_k<<<1024, 256, 0, stream>>>(c2w, WT4, 256, 32);
        convmfma_k<256><<<dim3(361, 1), 256, 0, stream>>>(A, WT4, C, 32);
        bnstats_k<<<32, 256, 0, stream>>>(C, bn2g, bn2b, scale, shift, 32);
        bn_tanh_ws_k<<<1024, 256, 0, stream>>>(C, scale, shift, ze0f, TOT32);
    } else {
        for (int i = 0; i < 3; i++) {
            wtr_k<<<576, 256, 0, stream>>>(rb1w + (i64)i * 589824, WT, 256, 256);
            convgemm_k<256><<<dim3(361, 2), 256, 0, stream>>>(A, WT, R, 256, 0, 256);
            bnstats_k<<<256, 256, 0, stream>>>(R, rbn1g + i * 256, rbn1b + i * 256, scale, shift, 256);
            bn_relu4_k<<<1024, 256, 0, stream>>>((float4*)R, scale, shift, 256, TOT256 / 4);
            wtr_k<<<576, 256, 0, stream>>>(rb2w + (i64)i * 589824, WT, 256, 256);
            convgemm_k<256><<<dim3(361, 2), 256, 0, stream>>>(R, WT, C, 256, 0, 256);
            bnstats_k<<<256, 256, 0, stream>>>(C, rbn2g + i * 256, rbn2b + i * 256, scale, shift, 256);
            bn_add_relu4_k<<<1024, 256, 0, stream>>>((float4*)A, (const float4*)C, scale, shift, 256, TOT256 / 4);
        }
        wtr_k<<<72, 256, 0, stream>>>(c2w, WT, 32, 256);
        convgemm_k<256><<<dim3(361, 1), 256, 0, stream>>>(A, WT, C, 32, 0, 32);
        bnstats_k<<<32, 256, 0, stream>>>(C, bn2g, bn2b, scale, shift, 32);
        bn_tanh_ws_k<<<1024, 256, 0, stream>>>(C, scale, shift, ze0f, TOT32);
    }

    vq0_k<<<181, 256, 0, stream>>>(ze0f, E0, ee0, zq0f, k0i);

    gemm_part_k<<<dim3(4, 32), 256, 0, stream>>>(ze0f, fc1w, part, 11552, 256, 361);
    combine_k<<<128, 256, 0, stream>>>(part, fc1b, h1a, 128 * 256, 256, 32, 1);
    gemm_part_k<<<dim3(8, 4), 256, 0, stream>>>(h1a, fc2w, part, 256, 512, 64);
    combine_k<<<256, 256, 0, stream>>>(part, fc2b, ze1f, 128 * 512, 512, 4, 2);
    vq64_k<<<4, 256, 0, stream>>>(ze1f, E1, ee1, zq1f, k1i);

    gemm_part_k<<<dim3(2, 8), 256, 0, stream>>>(ze1f, h2fw, part, 512, 128, 64);
    combine_k<<<64, 256, 0, stream>>>(part, h2fb, h2a, 128 * 128, 128, 8, 1);
    gemm_part_k<<<dim3(8, 2), 256, 0, stream>>>(h2a, h2f2w, part, 128, 512, 64);
    combine_k<<<256, 256, 0, stream>>>(part, h2f2b, ze2f, 128 * 512, 512, 2, 2);
    vq64_k<<<4, 256, 0, stream>>>(ze2f, E2, ee2, zq2f, k2i);

    gemm_part_k<<<dim3(2, 8), 256, 0, stream>>>(zq2f, h2f3w, part, 512, 128, 64);
    combine_k<<<64, 256, 0, stream>>>(part, h2f3b, h2b, 128 * 128, 128, 8, 1);
    gemm_part_k<<<dim3(8, 2), 256, 0, stream>>>(h2b, h2f4w, part, 128, 512, 64);
    combine_k<<<256, 256, 0, stream>>>(part, h2f4b, decf, 128 * 512, 512, 2, 2);
    blend_k<<<256, 256, 0, stream>>>(zq1f, decf, hier, 1, x1f, 512, 65536);

    gemm_part_k<<<dim3(4, 8), 256, 0, stream>>>(x1f, h1f3w, part, 512, 256, 64);
    combine_k<<<128, 256, 0, stream>>>(part, h1f3b, h1b, 128 * 256, 256, 8, 1);
    gemm_part_k<<<dim3(181, 2), 256, 0, stream>>>(h1b, h1f4w, part, 256, 11552, 128);
    combine_k<<<1024, 256, 0, stream>>>(part, h1f4b, dec0, TOT32, 11552, 2, 2);
    blend_k<<<1024, 256, 0, stream>>>(zq0f, dec0, hier, 0, xf, 11552, TOT32);

    gemm_part_k<<<dim3(6, 16), 256, 0, stream>>>(xf, polw, part, 11552, 362, 722);
    combine_k<<<256, 256, 0, stream>>>(part, polb, polf, 128 * 362, 362, 16, 0);
    value_k<<<128, 256, 0, stream>>>(xf, valw, valb, valf);

    // ---- emit phase (overwrites WT4 region; sole d_out writers from here) ----
    emit_f32_k<<<128, 256, 0, stream>>>(polf, out, OUT_POLICY, 46336);
    emit_f32_k<<<1, 128, 0, stream>>>(valf, out, OUT_VALUE, 128);
    emit_f32_k<<<1024, 256, 0, stream>>>(ze0f, out, OUT_ZE0, TOT32);
    emit_f32_k<<<256, 256, 0, stream>>>(ze1f, out, OUT_ZE1, 65536);
    emit_f32_k<<<256, 256, 0, stream>>>(ze2f, out, OUT_ZE2, 65536);
    emit_dup_k<<<1024, 256, 0, stream>>>(zq0f, out, OUT_ZQ0, OUT_ZQL0, TOT32);
    emit_dup_k<<<256, 256, 0, stream>>>(zq1f, out, OUT_ZQ1, OUT_ZQL1, 65536);
    emit_dup_k<<<256, 256, 0, stream>>>(zq2f, out, OUT_ZQ2, OUT_ZQL2, 65536);
    emit_k_k<<<181, 256, 0, stream>>>(k0i, out, OUT_K0, 46208);
    emit_k_k<<<4, 256, 0, stream>>>(k1i, out, OUT_K1, 1024);
    emit_k_k<<<4, 256, 0, stream>>>(k2i, out, OUT_K2, 1024);
    emit_em_k<<<1024, 256, 0, stream>>>(cm0, out, OUT_EM0, 32, 361, TOT32);
    emit_em_k<<<256, 256, 0, stream>>>(cm1, out, OUT_EM1, 64, 8, 65536);
    emit_em_k<<<256, 256, 0, stream>>>(cm2, out, OUT_EM2, 64, 8, 65536);
}